// Round 8
// baseline (274.321 us; speedup 1.0000x reference)
//
#include <hip/hip_runtime.h>
#include <hip/hip_bf16.h>

// Problem constants
constexpr int kB   = 2;
constexpr int kS   = 2048;
constexpr int kD   = 1024;
constexpr int kH   = 16;
constexpr int kDh  = 64;
constexpr int kBS  = kB * kS;          // 4096 rows

typedef __attribute__((ext_vector_type(8))) short short8;   // 8 bf16 = 4 VGPRs
typedef __attribute__((ext_vector_type(4))) float floatx4;  // MFMA acc

__device__ inline unsigned short f2b(float f) {
    __hip_bfloat16 h = __float2bfloat16(f);
    return *reinterpret_cast<unsigned short*>(&h);
}

__device__ inline float b2f(unsigned short u) {
    union { unsigned u; float f; } cv;
    cv.u = (unsigned)u << 16;
    return cv.f;
}

__device__ inline floatx4 mfma16(short8 a, short8 b, floatx4 c) {
    return __builtin_amdgcn_mfma_f32_16x16x32_bf16(a, b, c, 0, 0, 0);
}

// async global->LDS, 16B per lane; LDS dest = wave-uniform base + lane*16
__device__ inline void gload16(const unsigned short* g, unsigned short* l) {
    __builtin_amdgcn_global_load_lds(
        (const __attribute__((address_space(1))) void*)g,
        (__attribute__((address_space(3))) void*)l, 16, 0, 0);
}

// ---------------------------------------------------------------------------
// K0: fp32 -> bf16 conversion of x (4M elems) and the 4 weights (4 x 1M elems)
// ---------------------------------------------------------------------------
__global__ void convert_kernel(const float* __restrict__ x,
                               const float* __restrict__ wq, const float* __restrict__ wk,
                               const float* __restrict__ wv, const float* __restrict__ wo,
                               unsigned short* __restrict__ xb, unsigned short* __restrict__ wb) {
    int gid = blockIdx.x * blockDim.x + threadIdx.x;
    long i4 = (long)gid * 4;
    const float* src;
    unsigned short* dst;
    long off;
    if (i4 < (long)kBS * kD) {
        src = x; dst = xb; off = i4;
    } else {
        long w = i4 - (long)kBS * kD;
        int sel = (int)(w >> 20);
        off = w & 1048575;
        src = (sel == 0) ? wq : (sel == 1) ? wk : (sel == 2) ? wv : wo;
        dst = wb + (long)sel * 1048576;
    }
    float4 v = *(const float4*)(src + off);
    ushort4 o;
    o.x = f2b(v.x); o.y = f2b(v.y); o.z = f2b(v.z); o.w = f2b(v.w);
    *(ushort4*)(dst + off) = o;
}

// ---------------------------------------------------------------------------
// K1: NT GEMM  C[M,N] = A[M,K] @ B[N,K]^T   (bf16 in, fp32 accum)
// m97-style staging: global_load_lds width=16, XOR-swizzled k-chunks.
// MODE 0: bf16 C; z==0 (Q) scaled by 0.125*log2(e) (attention scale folded,
//         exp2 domain). MODE 1: fp32 C + residual.
// ---------------------------------------------------------------------------
template <int MODE>
__launch_bounds__(256, 2)
__global__ void gemm_nt(const unsigned short* __restrict__ A,
                        const unsigned short* __restrict__ Bw,
                        void* __restrict__ Cout,
                        const float* __restrict__ resid,
                        int M, int N, int K) {
    __shared__ __align__(16) unsigned short As[128 * 32];
    __shared__ __align__(16) unsigned short Bs[128 * 32];

    const int z  = blockIdx.z;
    const unsigned short* Bp = Bw + (size_t)z * N * K;
    const int m0 = blockIdx.y * 128, n0 = blockIdx.x * 128;
    const int tid  = threadIdx.x;
    const int lane = tid & 63, wv = tid >> 6;
    const int wm = wv >> 1, wn = wv & 1;
    const int quad = lane >> 4, l16 = lane & 15;

    floatx4 acc[4][4] = {};

    const int c0 = wv * 64 + lane;          // 0..255   (rows 0..63)
    const int c1 = 256 + c0;                // 256..511 (rows 64..127)
    const int ar0 = c0 >> 2, aj0 = ((c0 & 3) ^ (ar0 & 3)) * 8;
    const int ar1 = c1 >> 2, aj1 = ((c1 & 3) ^ (ar1 & 3)) * 8;
    const unsigned short* Ag0 = A  + (size_t)(m0 + ar0) * K + aj0;
    const unsigned short* Ag1 = A  + (size_t)(m0 + ar1) * K + aj1;
    const unsigned short* Bg0 = Bp + (size_t)(n0 + ar0) * K + aj0;
    const unsigned short* Bg1 = Bp + (size_t)(n0 + ar1) * K + aj1;
    unsigned short* Asd0 = As + wv * 512;
    unsigned short* Asd1 = As + (4 + wv) * 512;
    unsigned short* Bsd0 = Bs + wv * 512;
    unsigned short* Bsd1 = Bs + (4 + wv) * 512;

    for (int k0 = 0; k0 < K; k0 += 32) {
        __syncthreads();
        gload16(Ag0 + k0, Asd0);
        gload16(Ag1 + k0, Asd1);
        gload16(Bg0 + k0, Bsd0);
        gload16(Bg1 + k0, Bsd1);
        __syncthreads();

        short8 af[4], bf[4];
#pragma unroll
        for (int i = 0; i < 4; i++) {
            const int R = wm * 64 + i * 16 + l16;
            af[i] = *(const short8*)(As + R * 32 + (quad ^ (l16 & 3)) * 8);
        }
#pragma unroll
        for (int j = 0; j < 4; j++) {
            const int R = wn * 64 + j * 16 + l16;
            bf[j] = *(const short8*)(Bs + R * 32 + (quad ^ (l16 & 3)) * 8);
        }
#pragma unroll
        for (int i = 0; i < 4; i++)
#pragma unroll
            for (int j = 0; j < 4; j++)
                acc[i][j] = mfma16(af[i], bf[j], acc[i][j]);
    }

#pragma unroll
    for (int i = 0; i < 4; i++)
#pragma unroll
        for (int j = 0; j < 4; j++) {
            const int row = m0 + wm * 64 + i * 16 + quad * 4;
            const int col = n0 + wn * 64 + j * 16 + l16;
#pragma unroll
            for (int r = 0; r < 4; r++) {
                float v = acc[i][j][r];
                if (MODE == 0) {
                    if (z == 0) v *= 0.18033688f;   // 0.125 * log2(e): exp2 domain
                    ((unsigned short*)Cout)[(size_t)z * M * N + (size_t)(row + r) * N + col] = f2b(v);
                } else {
                    size_t idx = (size_t)(row + r) * N + col;
                    ((float*)Cout)[idx] = v + resid[idx];
                }
            }
        }
}

// ---------------------------------------------------------------------------
// K2: partial column-softmax sums, q-split 2-way for wave parallelism.
// psum[qslice][bh*2048+key] = sum over half the q range of exp2(s[q,k]).
// Grid (1024, 2); XCD-swizzled bh decode on x.
// ---------------------------------------------------------------------------
__launch_bounds__(128, 4)
__global__ void stats_kernel(const unsigned short* __restrict__ Qb,
                             const unsigned short* __restrict__ Kb,
                             float* __restrict__ psum) {
    __shared__ __align__(16) unsigned short Qs[64 * 64];

    const int id = blockIdx.x;                       // 0..1023
    const int bh = (id & 7) + 8 * ((id >> 3) & 3);   // XCD-grouped
    const int keyblk = id >> 5;                      // 0..31
    const int qsl = blockIdx.y;                      // 0..1
    const int b = bh >> 4, h = bh & 15;
    const int tid = threadIdx.x, lane = tid & 63, w = tid >> 6;   // w = 0..1
    const int quad = lane >> 4, l16 = lane & 15;
    const int keybase = keyblk * 64 + w * 32;

    // A-frags: K rows (2 key-tiles x 2 dh-halves), held in regs
    short8 ak[2][2];
#pragma unroll
    for (int s = 0; s < 2; s++) {
        const unsigned short* Krow = Kb + (size_t)(b * kS + keybase + s * 16 + l16) * kD + h * kDh;
        ak[s][0] = *(const short8*)(Krow + quad * 8);
        ak[s][1] = *(const short8*)(Krow + 32 + quad * 8);
    }

    const int r0 = lane >> 3;
    const int jc = ((lane & 7) ^ r0) * 8;
    const unsigned short* Qg[4];
    unsigned short* Ql[4];
#pragma unroll
    for (int seg = 0; seg < 4; seg++) {
        const int row = seg * 16 + w * 8 + r0;              // 0..63
        Qg[seg] = Qb + (size_t)(b * kS + row) * kD + h * kDh + jc;   // + q0*kD per chunk
        Ql[seg] = Qs + (seg * 16 + w * 8) * 64;             // wave-uniform
    }

    const int pk0 = (quad ^ (l16 & 7)) * 8;
    const int pk1 = ((4 + quad) ^ (l16 & 7)) * 8;

    float lacc[2][4] = {};
    const int qstart = qsl * (kS / 2);

    for (int q0 = qstart; q0 < qstart + kS / 2; q0 += 64) {
        __syncthreads();
#pragma unroll
        for (int seg = 0; seg < 4; seg++)
            gload16(Qg[seg] + (size_t)q0 * kD, Ql[seg]);
        __syncthreads();

#pragma unroll
        for (int c = 0; c < 4; c++) {
            const unsigned short* row = Qs + (c * 16 + l16) * 64;
            short8 bq0 = *(const short8*)(row + pk0);
            short8 bq1 = *(const short8*)(row + pk1);
#pragma unroll
            for (int s = 0; s < 2; s++) {
                floatx4 t = {0.f, 0.f, 0.f, 0.f};
                t = mfma16(ak[s][0], bq0, t);
                t = mfma16(ak[s][1], bq1, t);
#pragma unroll
                for (int r = 0; r < 4; r++)
                    lacc[s][r] += exp2f(t[r]);
            }
        }
    }

#pragma unroll
    for (int off = 1; off <= 8; off <<= 1)
#pragma unroll
        for (int s = 0; s < 2; s++)
#pragma unroll
            for (int r = 0; r < 4; r++)
                lacc[s][r] += __shfl_xor(lacc[s][r], off, 64);

    if (l16 == 0) {
#pragma unroll
        for (int s = 0; s < 2; s++)
#pragma unroll
            for (int r = 0; r < 4; r++)
                psum[(size_t)qsl * 32 * kS + (size_t)bh * kS + keybase + s * 16 + quad * 4 + r] =
                    lacc[s][r];
    }
}

// K2c: invl = 1 / (psum0 + psum1)
__global__ void invl_kernel(const float* __restrict__ psum, float* __restrict__ invl) {
    int i = blockIdx.x * 256 + threadIdx.x;   // 65536 total
    invl[i] = 1.0f / (psum[i] + psum[32 * kS + i]);
}

// ---------------------------------------------------------------------------
// K2b: VT[bh][d][k] = V[b][k][h*64+d] * invl[bh][k]   (pre-scaled V^T)
// ---------------------------------------------------------------------------
__global__ void vt_kernel(const unsigned short* __restrict__ Vb,
                          const float* __restrict__ invl,
                          unsigned short* __restrict__ VT) {
    __shared__ unsigned short tile[64 * 65];
    const int bh = blockIdx.y, b = bh >> 4, h = bh & 15;
    const int k0 = blockIdx.x * 64;
    const int tid = threadIdx.x;
    const int kr = tid >> 2, dc = (tid & 3) * 16;

    const float iv = invl[(size_t)bh * kS + k0 + kr];
    const unsigned short* src = Vb + (size_t)(b * kS + k0 + kr) * kD + h * kDh + dc;
    uint4 v0 = *(const uint4*)(src);
    uint4 v1 = *(const uint4*)(src + 8);
    unsigned short vs[16];
    *(uint4*)(vs) = v0; *(uint4*)(vs + 8) = v1;
#pragma unroll
    for (int i = 0; i < 16; i++)
        tile[kr * 65 + dc + i] = f2b(b2f(vs[i]) * iv);
    __syncthreads();
    const int d = tid >> 2, kc = (tid & 3) * 16;
    unsigned short os[16];
#pragma unroll
    for (int j = 0; j < 16; j++) os[j] = tile[(kc + j) * 65 + d];
    unsigned short* dst = VT + (size_t)bh * kDh * kS + (size_t)d * kS + k0 + kc;
    *(uint4*)(dst)     = *(uint4*)(os);
    *(uint4*)(dst + 8) = *(uint4*)(os + 8);
}

// ---------------------------------------------------------------------------
// K3: ctx = exp2(S) @ VT^T — k-split 2-way (blockIdx.y = k-slice) for wave
// parallelism: grid 2048 -> 6 blocks/CU (LDS-capped), half the per-block
// serial chain. Each slice writes a bf16 partial; combine_kernel sums them.
// ---------------------------------------------------------------------------
__launch_bounds__(128, 3)
__global__ void ctx_kernel(const unsigned short* __restrict__ Qb,
                           const unsigned short* __restrict__ Kb,
                           const unsigned short* __restrict__ VT,
                           unsigned short* __restrict__ CtxA,
                           unsigned short* __restrict__ CtxB) {
    constexpr int LDP = 72;
    __shared__ __align__(16) unsigned short Ks[64 * 64];
    __shared__ __align__(16) unsigned short VTs[64 * 64];
    __shared__ __align__(16) unsigned short Pt[2][32 * LDP];

    const int id = blockIdx.x;                       // 0..1023
    const int bh = (id & 7) + 8 * ((id >> 3) & 3);   // XCD-grouped
    const int qblk = id >> 5;                        // 0..31
    const int ks = blockIdx.y;                       // k-slice 0..1
    const int b = bh >> 4, h = bh & 15;
    const int tid = threadIdx.x, lane = tid & 63, w = tid >> 6;   // w = 0..1
    const int quad = lane >> 4, l16 = lane & 15;
    const int qbase = qblk * 64 + w * 32;

    short8 aq[2][2];
#pragma unroll
    for (int s = 0; s < 2; s++) {
        const unsigned short* Qrow = Qb + (size_t)(b * kS + qbase + s * 16 + l16) * kD + h * kDh;
        aq[s][0] = *(const short8*)(Qrow + quad * 8);
        aq[s][1] = *(const short8*)(Qrow + 32 + quad * 8);
    }
    floatx4 acc[2][4] = {};

    const unsigned short* Kbase = Kb + (size_t)(b * kS) * kD + h * kDh;
    const unsigned short* VTb   = VT + (size_t)bh * kDh * kS;

    const int r0 = lane >> 3;
    const int jc = ((lane & 7) ^ r0) * 8;
    const unsigned short* Kg[4];
    const unsigned short* Vg[4];
    unsigned short* Kl[4];
    unsigned short* Vl[4];
#pragma unroll
    for (int seg = 0; seg < 4; seg++) {
        const int row = seg * 16 + w * 8 + r0;         // 0..63
        Kg[seg] = Kbase + (size_t)row * kD + jc;       // + k0*kD per chunk
        Vg[seg] = VTb + (size_t)row * kS + jc;         // + k0 per chunk
        Kl[seg] = Ks  + (seg * 16 + w * 8) * 64;       // wave-uniform
        Vl[seg] = VTs + (seg * 16 + w * 8) * 64;
    }

    unsigned short* P = Pt[w];
    unsigned short* pw[4];
#pragma unroll
    for (int c = 0; c < 4; c++)
        pw[c] = P + quad * 4 * LDP + (c ^ quad) * 16 + l16;
    const int sw_r = (l16 >> 2) * 16;
    const unsigned short* pr0 = P + l16 * LDP + ((quad * 8) ^ sw_r);
    const unsigned short* pr1 = P + l16 * LDP + ((32 + quad * 8) ^ sw_r);

    const int pk0 = (quad ^ (l16 & 7)) * 8;
    const int pk1 = ((4 + quad) ^ (l16 & 7)) * 8;

    const int kstart = ks * (kS / 2);
    for (int k0 = kstart; k0 < kstart + kS / 2; k0 += 64) {
        __syncthreads();
#pragma unroll
        for (int seg = 0; seg < 4; seg++) {
            gload16(Kg[seg] + (size_t)k0 * kD, Kl[seg]);
            gload16(Vg[seg] + k0, Vl[seg]);
        }
        __syncthreads();

        short8 bk[4][2];
#pragma unroll
        for (int c = 0; c < 4; c++) {
            const unsigned short* row = Ks + (c * 16 + l16) * 64;
            bk[c][0] = *(const short8*)(row + pk0);
            bk[c][1] = *(const short8*)(row + pk1);
        }
        floatx4 sc[2][4];
#pragma unroll
        for (int s = 0; s < 2; s++)
#pragma unroll
            for (int c = 0; c < 4; c++) {
                floatx4 t = {0.f, 0.f, 0.f, 0.f};
                t = mfma16(aq[s][0], bk[c][0], t);
                sc[s][c] = mfma16(aq[s][1], bk[c][1], t);
            }
#pragma unroll
        for (int s = 0; s < 2; s++)
#pragma unroll
            for (int c = 0; c < 4; c++)
#pragma unroll
                for (int r = 0; r < 4; r++) {
                    union { float f; unsigned u; } cv;
                    cv.f = exp2f(sc[s][c][r]);
                    pw[c][(s * 16 + r) * LDP] = (unsigned short)(cv.u >> 16);
                }

        short8 bv[4][2];
#pragma unroll
        for (int t = 0; t < 4; t++) {
            const unsigned short* row = VTs + (t * 16 + l16) * 64;
            bv[t][0] = *(const short8*)(row + pk0);
            bv[t][1] = *(const short8*)(row + pk1);
        }
#pragma unroll
        for (int s = 0; s < 2; s++) {
            short8 ap0 = *(const short8*)(pr0 + s * 16 * LDP);
            short8 ap1 = *(const short8*)(pr1 + s * 16 * LDP);
#pragma unroll
            for (int t = 0; t < 4; t++) {
                acc[s][t] = mfma16(ap0, bv[t][0], acc[s][t]);
                acc[s][t] = mfma16(ap1, bv[t][1], acc[s][t]);
            }
        }
    }

    unsigned short* Cdst = ks ? CtxB : CtxA;
#pragma unroll
    for (int s = 0; s < 2; s++)
#pragma unroll
        for (int t = 0; t < 4; t++)
#pragma unroll
            for (int r = 0; r < 4; r++)
                Cdst[(size_t)(b * kS + qbase + s * 16 + quad * 4 + r) * kD + h * kDh + t * 16 + l16] =
                    f2b(acc[s][t][r]);
}

// K3b: Ctx = CtxA + CtxB (bf16, in place into CtxA)
__global__ void combine_kernel(unsigned short* __restrict__ CtxA,
                               const unsigned short* __restrict__ CtxB) {
    size_t i = ((size_t)blockIdx.x * 256 + threadIdx.x) * 8;
    unsigned short a[8], c[8];
    *(uint4*)a = *(const uint4*)(CtxA + i);
    *(uint4*)c = *(const uint4*)(CtxB + i);
#pragma unroll
    for (int j = 0; j < 8; j++)
        a[j] = f2b(b2f(a[j]) + b2f(c[j]));
    *(uint4*)(CtxA + i) = *(uint4*)a;
}

// ---------------------------------------------------------------------------
// K4: row LayerNorm
// ---------------------------------------------------------------------------
__global__ void ln_kernel(const float* __restrict__ R, const float* __restrict__ gamma,
                          const float* __restrict__ beta, float* __restrict__ out) {
    const int row = blockIdx.x;
    const int tid = threadIdx.x;
    const float4 v = ((const float4*)(R + (size_t)row * kD))[tid];
    float s  = v.x + v.y + v.z + v.w;
    float ss = v.x * v.x + v.y * v.y + v.z * v.z + v.w * v.w;
#pragma unroll
    for (int off = 32; off > 0; off >>= 1) {
        s  += __shfl_down(s, off, 64);
        ss += __shfl_down(ss, off, 64);
    }
    __shared__ float ws_s[4], ws_ss[4];
    __shared__ float mu_sh, inv_sh;
    const int lane = tid & 63, w = tid >> 6;
    if (lane == 0) { ws_s[w] = s; ws_ss[w] = ss; }
    __syncthreads();
    if (tid == 0) {
        float S1 = ws_s[0] + ws_s[1] + ws_s[2] + ws_s[3];
        float S2 = ws_ss[0] + ws_ss[1] + ws_ss[2] + ws_ss[3];
        float mu = S1 * (1.0f / kD);
        float var = S2 * (1.0f / kD) - mu * mu;
        mu_sh = mu;
        inv_sh = rsqrtf(var + 1e-5f);
    }
    __syncthreads();
    const float mu = mu_sh, inv = inv_sh;
    const float4 g  = ((const float4*)gamma)[tid];
    const float4 bb = ((const float4*)beta)[tid];
    float4 o;
    o.x = (v.x - mu) * inv * g.x + bb.x;
    o.y = (v.y - mu) * inv * g.y + bb.y;
    o.z = (v.z - mu) * inv * g.z + bb.z;
    o.w = (v.w - mu) * inv * g.w + bb.w;
    ((float4*)(out + (size_t)row * kD))[tid] = o;
}

// ---------------------------------------------------------------------------
// Workspace layout (~72.8 MB peak, aliasing is stream-ordered-safe):
//   [0,   8MB)  Xb bf16
//   [8,  16MB)  Wb bf16 wq|wk|wv|wo
//   [16, 40MB)  QKV bf16 Q|K|V  (Q pre-scaled by 0.125*log2e)
//   [40, 48MB)  CtxA bf16 (k-slice 0; becomes summed Ctx after combine)
//   [48, 64MB)  VT bf16 [32][64][2048]; ALIASES R (written strictly later)
//   [64, 72MB)  CtxB bf16 (k-slice 1)
//   [72MB, +512KB)   psum fp32 [2][32*2048]
//   [72.5MB, +256KB) invl fp32 [32*2048]
// ---------------------------------------------------------------------------
extern "C" void kernel_launch(void* const* d_in, const int* in_sizes, int n_in,
                              void* d_out, int out_size, void* d_ws, size_t ws_size,
                              hipStream_t stream) {
    const float* x     = (const float*)d_in[0];
    const float* wq    = (const float*)d_in[1];
    const float* wk    = (const float*)d_in[2];
    const float* wv    = (const float*)d_in[3];
    const float* wo    = (const float*)d_in[4];
    const float* gamma = (const float*)d_in[5];
    const float* beta  = (const float*)d_in[6];
    float* out = (float*)d_out;

    char* ws = (char*)d_ws;
    unsigned short* Xb  = (unsigned short*)(ws);
    unsigned short* Wb  = (unsigned short*)(ws + (8u  << 20));
    unsigned short* QKV = (unsigned short*)(ws + (16u << 20));
    unsigned short* Qb  = QKV;
    unsigned short* Kb  = QKV + (size_t)kBS * kD;
    unsigned short* Vb  = QKV + (size_t)2 * kBS * kD;
    unsigned short* CtxA = (unsigned short*)(ws + (40u << 20));
    unsigned short* VT  = (unsigned short*)(ws + (48u << 20));
    float* R            = (float*)(ws + (48u << 20));  // aliases VT
    unsigned short* CtxB = (unsigned short*)(ws + (64u << 20));
    float* psum         = (float*)(ws + (72u << 20));
    float* invl         = (float*)(ws + (72u << 20) + (512u << 10));

    convert_kernel<<<8192, 256, 0, stream>>>(x, wq, wk, wv, wo, Xb, Wb);

    gemm_nt<0><<<dim3(kD / 128, kBS / 128, 3), 256, 0, stream>>>(
        Xb, Wb, QKV, nullptr, kBS, kD, kD);

    stats_kernel<<<dim3(1024, 2), 128, 0, stream>>>(Qb, Kb, psum);

    invl_kernel<<<(32 * kS) / 256, 256, 0, stream>>>(psum, invl);

    vt_kernel<<<dim3(kS / 64, kB * kH), 256, 0, stream>>>(Vb, invl, VT);

    ctx_kernel<<<dim3(1024, 2), 128, 0, stream>>>(Qb, Kb, VT, CtxA, CtxB);

    combine_kernel<<<(kBS * kD) / (256 * 8), 256, 0, stream>>>(CtxA, CtxB);

    gemm_nt<1><<<dim3(kD / 128, kBS / 128, 1), 256, 0, stream>>>(
        CtxA, Wb + (size_t)3 * kD * kD, R, x, kBS, kD, kD);

    ln_kernel<<<kBS, 256, 0, stream>>>(R, gamma, beta, out);
}